// Round 5
// baseline (236.706 us; speedup 1.0000x reference)
//
#include <hip/hip_runtime.h>
#include <stdint.h>

// FourierBlock: B=32, D=64, N=128, L=192, M=32 modes. SINGLE fused kernel.
// grid 256 = (n 128, bh 2), 512 thr (8 waves), 1 block/CU, no workspace.
// Per block (n, b-half of 16):
//  P1: DFT  X[(i,b),cat] = q·F   (MFMA, qb+F in LDS, X -> LDS [cat][b][i])
//  P2: X -> registers (wave w holds cats 8w..8w+7 as ready A-frags, 64 VGPR)
//  P3: loop 4 o-chunks: { stage W[n][:, o16,:] -> LDS [c][o][m][i] (128KB) |
//      complex mix MFMA -> Y regs | Y -> LDS [b][o][cat] | iDFT MFMA with
//      sincos basis frags (96 VGPR) | f32x4 full-line stores to out }
// HBM: q 201 + W 134(+134 L3) + out 201 ~= 536 MB.

typedef __attribute__((ext_vector_type(8))) short short8;
typedef __attribute__((ext_vector_type(4))) float f32x4;
typedef __attribute__((ext_vector_type(4))) unsigned short u16x4;

__device__ __forceinline__ unsigned short f2bf(float f) {
  union { float fv; uint32_t u; } v; v.fv = f;
  uint32_t u = v.u;
  u += 0x7fffu + ((u >> 16) & 1u);          // round-to-nearest-even
  return (unsigned short)(u >> 16);
}

__device__ __forceinline__ f32x4 zero4() { f32x4 z; z[0]=0.f; z[1]=0.f; z[2]=0.f; z[3]=0.f; return z; }

#define TWO_PI_OVER_L (6.283185307179586f / 192.0f)

// LDS strides (u16 units), all 16B-aligned, bank-audited:
#define QB_RSTR   40      // qb row (i*16+b), 80 B: quads 5b%8 distinct
#define F_CSTR    200     // F cat stride, 400 B
#define X_CSTR    1176    // X cat stride, 2352 B (write 4-way, read min)
#define X_BSTR    72      // X b stride, 144 B
#define W_CSTR    36992   // W c stride = 16*2312
#define W_OSTR    2312    // W o stride = 32*72+8
#define W_MSTR    72      // W m stride = 64 i + 8 pad
#define Y_BSTR    1160    // Y b stride = 16*72+8
#define Y_OSTR    72      // Y o stride

__global__ __launch_bounds__(512, 2)
void fb_fused(const float* __restrict__ q, const float* __restrict__ wr,
              const float* __restrict__ wi, float* __restrict__ out) {
  extern __shared__ char smem[];
  unsigned short* qb = (unsigned short*)smem;            // phase 1 staging
  unsigned short* Fb = (unsigned short*)(smem + 81920);  // phase 1 basis
  unsigned short* X  = (unsigned short*)smem;            // phase 1 out / phase 2 in
  unsigned short* Wt = (unsigned short*)smem;            // phase 3 W chunk
  unsigned short* Yt = (unsigned short*)smem;            // phase 3 Y chunk

  const int t = threadIdx.x, lane = t & 63, w = t >> 6;
  const int l15 = lane & 15, g = lane >> 4;
  const int n = blockIdx.x >> 1, bh = blockIdx.x & 1;

  // ---- phase 0: DFT basis F[cat][l]  (cat=2m+c; c=0: cos, c=1: -sin)
  for (int idx = t; idx < 64 * 192; idx += 512) {
    int cat = idx / 192, l = idx - cat * 192;
    int m = cat >> 1;
    int r = (m * l) % 192;
    float ang = (float)r * TWO_PI_OVER_L;
    float v = (cat & 1) ? -__sinf(ang) : __cosf(ang);
    Fb[cat * F_CSTR + l] = f2bf(v);
  }

  // ---- phase 1: DFT.  rows = i*16+b (64 M-tiles), cols = cat 64, K = l 192.
  f32x4 acc1[8][4];
#pragma unroll
  for (int a = 0; a < 8; ++a)
#pragma unroll
    for (int bq = 0; bq < 4; ++bq) acc1[a][bq] = zero4();

  for (int kc = 0; kc < 6; ++kc) {
#pragma unroll
    for (int j = 0; j < 16; ++j) {
      int f = j * 512 + t;
      int lg = f & 7, b = (f >> 3) & 15, i = f >> 7;
      const float4 v = *(const float4*)(q + (((bh * 16 + b) * 64 + i) * 128 + n) * 192 + kc * 32 + lg * 4);
      u16x4 h; h[0] = f2bf(v.x); h[1] = f2bf(v.y); h[2] = f2bf(v.z); h[3] = f2bf(v.w);
      *(u16x4*)(qb + (i * 16 + b) * QB_RSTR + lg * 4) = h;
    }
    __syncthreads();

    short8 Bf[4];
#pragma unroll
    for (int nt = 0; nt < 4; ++nt) {
      int cat = nt * 16 + l15;
      Bf[nt] = *(const short8*)(Fb + cat * F_CSTR + kc * 32 + g * 8);
    }
#pragma unroll
    for (int mt = 0; mt < 8; ++mt) {
      int i = w * 8 + mt;
      short8 A = *(const short8*)(qb + (i * 16 + l15) * QB_RSTR + g * 8);
#pragma unroll
      for (int nt = 0; nt < 4; ++nt)
        acc1[mt][nt] = __builtin_amdgcn_mfma_f32_16x16x32_bf16(A, Bf[nt], acc1[mt][nt], 0, 0, 0);
    }
    __syncthreads();
  }

  // ---- phase 1 epilogue: X -> LDS [cat][b][i]
#pragma unroll
  for (int mt = 0; mt < 8; ++mt) {
    int i = w * 8 + mt;
#pragma unroll
    for (int nt = 0; nt < 4; ++nt) {
      int cat = nt * 16 + l15;
      f32x4 v = acc1[mt][nt];
#pragma unroll
      for (int r = 0; r < 4; ++r)
        X[cat * X_CSTR + (g * 4 + r) * X_BSTR + i] = f2bf(v[r]);
    }
  }
  __syncthreads();

  // ---- phase 2: X -> registers. wave w owns cats 8w..8w+7 (= m 4w..4w+3).
  short8 Xr[4][2][2];  // [mm][cc][ic] : ready mix A-frags (row=b, k=i)
#pragma unroll
  for (int mm = 0; mm < 4; ++mm)
#pragma unroll
    for (int cc = 0; cc < 2; ++cc)
#pragma unroll
      for (int ic = 0; ic < 2; ++ic) {
        int cat = w * 8 + mm * 2 + cc;
        Xr[mm][cc][ic] = *(const short8*)(X + cat * X_CSTR + l15 * X_BSTR + ic * 32 + g * 8);
      }
  __syncthreads();   // X consumed; LDS free for W/Y

  // ---- iDFT basis A-frags (row = l, k = cat), computed once (acc1 dead)
  short8 Af[12][2];
#pragma unroll
  for (int Mt = 0; Mt < 12; ++Mt) {
    int lt = Mt * 16 + l15;
#pragma unroll
    for (int kc = 0; kc < 2; ++kc) {
#pragma unroll
      for (int e = 0; e < 8; ++e) {
        int cat = kc * 32 + g * 8 + e;
        int m = cat >> 1;
        int r = (m * lt) % 192;
        float ang = (float)r * TWO_PI_OVER_L;
        float coef = (m == 0) ? (1.0f / 192.0f) : (2.0f / 192.0f);
        float v = ((cat & 1) ? -__sinf(ang) : __cosf(ang)) * coef;
        Af[Mt][kc][e] = (short)f2bf(v);
      }
    }
  }

  // ---- phase 3: o-chunk loop (16 o's per chunk)
  for (int oq = 0; oq < 4; ++oq) {
    // stage W[n][i 0..63][oq*16+o][m 0..31][c2] fp32 -> Wt[c][o][m][i] bf16
#pragma unroll
    for (int j = 0; j < 32; ++j) {
      int f = j * 512 + t;
      int mg = f & 7, o = (f >> 3) & 15, i = (f >> 7) & 63, c = (f >> 13) & 1;
      const float* src = (c ? wi : wr) + ((n * 64 + i) * 64 + oq * 16 + o) * 32 + mg * 4;
      float4 v = *(const float4*)src;
      unsigned short* d = Wt + c * W_CSTR + o * W_OSTR + (mg * 4) * W_MSTR + i;
      d[0]          = f2bf(v.x);
      d[W_MSTR]     = f2bf(v.y);
      d[2 * W_MSTR] = f2bf(v.z);
      d[3 * W_MSTR] = f2bf(v.w);
    }
    __syncthreads();

    // complex mix: Y[b16, o16] per m; A from Xr regs, B from Wt (ds_read_b128)
    f32x4 accY[4][2];  // [mm][cc]
#pragma unroll
    for (int a = 0; a < 4; ++a)
#pragma unroll
      for (int c2 = 0; c2 < 2; ++c2) accY[a][c2] = zero4();

#pragma unroll
    for (int mm = 0; mm < 4; ++mm) {
      int m = w * 4 + mm;
#pragma unroll
      for (int ic = 0; ic < 2; ++ic) {
        const unsigned short* wb = Wt + l15 * W_OSTR + m * W_MSTR + ic * 32 + g * 8;
        short8 Br = *(const short8*)(wb);
        short8 Bi = *(const short8*)(wb + W_CSTR);
        short8 nBi;
#pragma unroll
        for (int e = 0; e < 8; ++e) nBi[e] = Bi[e] ^ (short)0x8000;
        accY[mm][0] = __builtin_amdgcn_mfma_f32_16x16x32_bf16(Xr[mm][0][ic], Br,  accY[mm][0], 0, 0, 0);
        accY[mm][0] = __builtin_amdgcn_mfma_f32_16x16x32_bf16(Xr[mm][1][ic], nBi, accY[mm][0], 0, 0, 0);
        accY[mm][1] = __builtin_amdgcn_mfma_f32_16x16x32_bf16(Xr[mm][0][ic], Bi,  accY[mm][1], 0, 0, 0);
        accY[mm][1] = __builtin_amdgcn_mfma_f32_16x16x32_bf16(Xr[mm][1][ic], Br,  accY[mm][1], 0, 0, 0);
      }
    }
    __syncthreads();   // all waves done reading Wt; Yt may overwrite

    // Y -> LDS [b][o_loc][cat]
#pragma unroll
    for (int mm = 0; mm < 4; ++mm)
#pragma unroll
      for (int cc = 0; cc < 2; ++cc) {
        int cat = (w * 4 + mm) * 2 + cc;
        f32x4 v = accY[mm][cc];
#pragma unroll
        for (int r = 0; r < 4; ++r)
          Yt[(g * 4 + r) * Y_BSTR + l15 * Y_OSTR + cat] = f2bf(v[r]);
      }
    __syncthreads();

    // iDFT: out[b][oq*16+o][n][l] ; wave w -> b {2w, 2w+1}
#pragma unroll
    for (int bb = 0; bb < 2; ++bb) {
      int b = w * 2 + bb;
      short8 Bf2[2];
#pragma unroll
      for (int kc = 0; kc < 2; ++kc)
        Bf2[kc] = *(const short8*)(Yt + b * Y_BSTR + l15 * Y_OSTR + kc * 32 + g * 8);
      float* dst = out + (((bh * 16 + b) * 64 + oq * 16 + l15) * 128 + n) * 192;
#pragma unroll
      for (int Mt = 0; Mt < 12; ++Mt) {
        f32x4 acc = zero4();
        acc = __builtin_amdgcn_mfma_f32_16x16x32_bf16(Af[Mt][0], Bf2[0], acc, 0, 0, 0);
        acc = __builtin_amdgcn_mfma_f32_16x16x32_bf16(Af[Mt][1], Bf2[1], acc, 0, 0, 0);
        *(f32x4*)(dst + Mt * 16 + g * 4) = acc;
      }
    }
    __syncthreads();   // Yt dead before next chunk's W stage
  }
}

// ---------------------------------------------------------------------------
extern "C" void kernel_launch(void* const* d_in, const int* in_sizes, int n_in,
                              void* d_out, int out_size, void* d_ws, size_t ws_size,
                              hipStream_t stream) {
  const float* q  = (const float*)d_in[0];
  const float* wr = (const float*)d_in[1];
  const float* wi = (const float*)d_in[2];
  float* out = (float*)d_out;

  hipFuncSetAttribute((const void*)fb_fused, hipFuncAttributeMaxDynamicSharedMemorySize, 150528);
  fb_fused<<<dim3(256), dim3(512), 150528, stream>>>(q, wr, wi, out);
}

// Round 6
// 225.123 us; speedup vs baseline: 1.0515x; 1.0515x over previous
//
#include <hip/hip_runtime.h>
#include <stdint.h>

// FourierBlock: B=32, D=64, N=128, L=192, M=32 modes.
// 3-kernel plan, round 6: mix kernel rebuilt for occupancy (r5 counters showed
// every mix variant ran 1-2 blocks/CU barrier-serialized at ~2 TB/s).
//   K1:  q -> Xp[n][m][c][ih][Mt][lane][e]  frag-packed bf16 DFT   (~235 MB)
//   K2g: complex mix, grid 512 = (n,oq) = exactly 2 blocks/CU (all resident):
//        c-split passes (stage Wr 64KB LDS -> MFMA -> stage Wi -> MFMA),
//        A-frags streamed from Xp, odd-dword LDS strides (conflict-light),
//        Yl overlay epilogue -> full-line Yp stores.                (~201 MB)
//   K3:  iDFT, Yp layout [n][oq][b][cat][o16], Yl stride 66 (bank fix).
// ws: Xp 33.5MB @0, Yp 33.5MB @16777216 u16.

typedef __attribute__((ext_vector_type(8))) short short8;
typedef __attribute__((ext_vector_type(4))) float f32x4;
typedef __attribute__((ext_vector_type(4))) unsigned short u16x4;

__device__ __forceinline__ unsigned short f2bf(float f) {
  union { float fv; uint32_t u; } v; v.fv = f;
  uint32_t u = v.u;
  u += 0x7fffu + ((u >> 16) & 1u);          // round-to-nearest-even
  return (unsigned short)(u >> 16);
}

__device__ __forceinline__ f32x4 zero4() { f32x4 z; z[0]=0.f; z[1]=0.f; z[2]=0.f; z[3]=0.f; return z; }

#define TWO_PI_OVER_L (6.283185307179586f / 192.0f)

// ---------------------------------------------------------------------------
// K1: DFT.  grid 256 = (n 128, ih 2), 512 thr (8 waves).  (r1/r3-proven)
// ---------------------------------------------------------------------------
__global__ __launch_bounds__(512, 2)
void k1_dft(const float* __restrict__ q, unsigned short* __restrict__ Xp) {
  extern __shared__ char smem[];
  const int t = threadIdx.x, lane = t & 63, w = t >> 6;
  const int n = blockIdx.x >> 1, ih = blockIdx.x & 1;

  unsigned short* qb = (unsigned short*)smem;
  char* Fb = smem + 65536;

  for (int idx = t; idx < 64 * 192; idx += 512) {
    int cat = idx / 192, l = idx - cat * 192;
    int m = cat >> 1;
    int r = (m * l) % 192;
    float ang = (float)r * TWO_PI_OVER_L;
    float v = (cat & 1) ? -__sinf(ang) : __cosf(ang);
    *(unsigned short*)(Fb + cat * 400 + l * 2) = f2bf(v);
  }

  f32x4 acc[8][4];
#pragma unroll
  for (int a = 0; a < 8; ++a)
#pragma unroll
    for (int bq = 0; bq < 4; ++bq) acc[a][bq] = zero4();

  for (int kc = 0; kc < 6; ++kc) {
#pragma unroll
    for (int j = 0; j < 16; ++j) {
      int f = j * 512 + t;
      int lg = f & 7, b = (f >> 3) & 31, il = f >> 8;
      const float4 v = *(const float4*)(q + (((b * 64 + ih * 32 + il) * 128 + n) * 192 + kc * 32 + lg * 4));
      u16x4 h; h[0] = f2bf(v.x); h[1] = f2bf(v.y); h[2] = f2bf(v.z); h[3] = f2bf(v.w);
      *(u16x4*)(qb + (il * 32 + b) * 32 + lg * 4) = h;
    }
    __syncthreads();

    short8 Bf[4];
#pragma unroll
    for (int nt = 0; nt < 4; ++nt) {
      int cat = nt * 16 + (lane & 15);
      Bf[nt] = *(const short8*)(Fb + cat * 400 + (kc * 32 + (lane >> 4) * 8) * 2);
    }
#pragma unroll
    for (int mt = 0; mt < 8; ++mt) {
      int Mt = w * 8 + mt;
      int il = Mt >> 1;
      int b = (Mt & 1) * 16 + (lane & 15);
      short8 A = *(const short8*)((const char*)qb + ((il * 32 + b) * 32 + (lane >> 4) * 8) * 2);
#pragma unroll
      for (int nt = 0; nt < 4; ++nt)
        acc[mt][nt] = __builtin_amdgcn_mfma_f32_16x16x32_bf16(A, Bf[nt], acc[mt][nt], 0, 0, 0);
    }
    __syncthreads();
  }

#pragma unroll
  for (int mt = 0; mt < 8; ++mt) {
    int Mt = w * 8 + mt;
    int il = Mt >> 1;
    int b0 = (Mt & 1) * 16 + (lane >> 4) * 4;
#pragma unroll
    for (int nt = 0; nt < 4; ++nt) {
      int cat = nt * 16 + (lane & 15);
      char* base = smem + cat * 2320 + il * 2;
      f32x4 v = acc[mt][nt];
#pragma unroll
      for (int r = 0; r < 4; ++r)
        *(unsigned short*)(base + (b0 + r) * 72) = f2bf(v[r]);
    }
  }
  __syncthreads();

  const int nbase = n * 131072;
#pragma unroll
  for (int j = 0; j < 16; ++j) {
    int f = j * 512 + t;
    int l2 = f & 63, Mt2 = (f >> 6) & 1, c = (f >> 7) & 1, m = f >> 8;
    int cat = 2 * m + c;
    int b = Mt2 * 16 + (l2 & 15);
    int i0 = (l2 >> 4) * 8;
    const char* base = smem + cat * 2320 + b * 72 + i0 * 2;
    u16x4 lo = *(const u16x4*)(base);
    u16x4 hi = *(const u16x4*)(base + 8);
    short8 vv;
    vv[0] = (short)lo[0]; vv[1] = (short)lo[1]; vv[2] = (short)lo[2]; vv[3] = (short)lo[3];
    vv[4] = (short)hi[0]; vv[5] = (short)hi[1]; vv[6] = (short)hi[2]; vv[7] = (short)hi[3];
    int off = nbase + ((((m * 2 + c) * 2 + ih) * 2 + Mt2) * 64 + l2) * 8;
    *(short8*)(Xp + off) = vv;
  }
}

// ---------------------------------------------------------------------------
// K2g: complex mix. grid 512 = (n 128, oq 4), 512 thr (8 waves), 2 blocks/CU.
// LDS: Wh rows R = o*33 + m, row stride 66 u16 (33 dw, odd -> bank-spread),
//      row = i 0..63 contiguous (+2 pad). 528 rows * 66 * 2B = 69696 B.
// Pass c=0: stage Wr -> MFMA (acc0 += Xr*Wr, acc1 += Xi*Wr)
// Pass c=1: stage Wi -> MFMA (acc0 += -Xi*Wi, acc1 += Xr*Wi)
// Epilogue: acc -> Yl overlay (b-stride 1036 u16) -> full-line Yp stores.
// Yp layout: [n][oq][b 32][cat 64][o 16].
// ---------------------------------------------------------------------------
__global__ __launch_bounds__(512, 4)
void k2g_mix(const float* __restrict__ wr, const float* __restrict__ wi,
             const unsigned short* __restrict__ Xp, unsigned short* __restrict__ Yp) {
  extern __shared__ char smem[];
  unsigned short* Wh = (unsigned short*)smem;
  const int t = threadIdx.x, lane = t & 63, w = t >> 6;
  const int l15 = lane & 15, g = lane >> 4;
  const int n = blockIdx.x >> 2, oq = blockIdx.x & 3;

  f32x4 acc[4][2][2];   // [mm][cc][Mt]
#pragma unroll
  for (int a = 0; a < 4; ++a)
#pragma unroll
    for (int c2 = 0; c2 < 2; ++c2)
#pragma unroll
      for (int b2 = 0; b2 < 2; ++b2) acc[a][c2][b2] = zero4();

#pragma unroll
  for (int pass = 0; pass < 2; ++pass) {
    if (pass) __syncthreads();              // protect Wh before restage
    // ---- stage W component: W[n][i][oq*16+o][m] fp32 -> Wh[(o*33+m)*66 + i]
    const float* wsrc = pass ? wi : wr;
#pragma unroll
    for (int j = 0; j < 16; ++j) {
      int f = j * 512 + t;
      int mg = f & 7, o = (f >> 3) & 15, i = f >> 7;
      float4 v = *(const float4*)(wsrc + ((n * 64 + i) * 64 + oq * 16 + o) * 32 + mg * 4);
      unsigned short* d = Wh + (o * 33 + mg * 4) * 66 + i;
      d[0]   = f2bf(v.x);
      d[66]  = f2bf(v.y);
      d[132] = f2bf(v.z);
      d[198] = f2bf(v.w);
    }
    __syncthreads();

    // ---- compute: wave w -> m = 4w..4w+3
#pragma unroll
    for (int mm = 0; mm < 4; ++mm) {
      int m = w * 4 + mm;
#pragma unroll
      for (int ic = 0; ic < 2; ++ic) {
        // A-frags from Xp (coalesced 1KB per load)
        const unsigned short* xb = Xp + n * 131072 + m * 4096 + ic * 1024 + lane * 8;
        short8 Ar0 = *(const short8*)(xb);
        short8 Ar1 = *(const short8*)(xb + 512);
        short8 Ai0 = *(const short8*)(xb + 2048);
        short8 Ai1 = *(const short8*)(xb + 2560);
        // B-frag from LDS: col o = l15, k = i = ic*32 + g*8 + e
        const unsigned int* p = (const unsigned int*)(Wh + (l15 * 33 + m) * 66 + ic * 32 + g * 8);
        union { unsigned int u[4]; short8 s; } bb;
        bb.u[0] = p[0]; bb.u[1] = p[1]; bb.u[2] = p[2]; bb.u[3] = p[3];
        short8 B = bb.s;
        if (pass == 0) {
          acc[mm][0][0] = __builtin_amdgcn_mfma_f32_16x16x32_bf16(Ar0, B, acc[mm][0][0], 0, 0, 0);
          acc[mm][0][1] = __builtin_amdgcn_mfma_f32_16x16x32_bf16(Ar1, B, acc[mm][0][1], 0, 0, 0);
          acc[mm][1][0] = __builtin_amdgcn_mfma_f32_16x16x32_bf16(Ai0, B, acc[mm][1][0], 0, 0, 0);
          acc[mm][1][1] = __builtin_amdgcn_mfma_f32_16x16x32_bf16(Ai1, B, acc[mm][1][1], 0, 0, 0);
        } else {
          short8 nAi0, nAi1;
#pragma unroll
          for (int e = 0; e < 8; ++e) { nAi0[e] = Ai0[e] ^ (short)0x8000; nAi1[e] = Ai1[e] ^ (short)0x8000; }
          acc[mm][0][0] = __builtin_amdgcn_mfma_f32_16x16x32_bf16(nAi0, B, acc[mm][0][0], 0, 0, 0);
          acc[mm][0][1] = __builtin_amdgcn_mfma_f32_16x16x32_bf16(nAi1, B, acc[mm][0][1], 0, 0, 0);
          acc[mm][1][0] = __builtin_amdgcn_mfma_f32_16x16x32_bf16(Ar0, B, acc[mm][1][0], 0, 0, 0);
          acc[mm][1][1] = __builtin_amdgcn_mfma_f32_16x16x32_bf16(Ar1, B, acc[mm][1][1], 0, 0, 0);
        }
      }
    }
  }
  __syncthreads();   // Wh dead; Yl overlay

  // ---- epilogue: acc -> Yl[b*1036 + cat*16 + o]
  unsigned short* Yl = (unsigned short*)smem;
#pragma unroll
  for (int mm = 0; mm < 4; ++mm)
#pragma unroll
    for (int cc = 0; cc < 2; ++cc) {
      int cat = 2 * (w * 4 + mm) + cc;
#pragma unroll
      for (int Mt = 0; Mt < 2; ++Mt) {
        f32x4 v = acc[mm][cc][Mt];
#pragma unroll
        for (int r = 0; r < 4; ++r) {
          int b = Mt * 16 + g * 4 + r;
          Yl[b * 1036 + cat * 16 + l15] = f2bf(v[r]);
        }
      }
    }
  __syncthreads();

  // ---- streamout: 32 b x 1024 u16 -> Yp[n][oq][b][cat][o16], full lines
  unsigned short* yb = Yp + ((n * 4 + oq) * 32) * 1024;
#pragma unroll
  for (int j = 0; j < 8; ++j) {
    int f = j * 512 + t;
    int b = f >> 7, r = f & 127;
    const unsigned short* s = Yl + b * 1036 + r * 8;
    u16x4 lo = *(const u16x4*)(s);
    u16x4 hi = *(const u16x4*)(s + 4);
    short8 v;
    v[0] = (short)lo[0]; v[1] = (short)lo[1]; v[2] = (short)lo[2]; v[3] = (short)lo[3];
    v[4] = (short)hi[0]; v[5] = (short)hi[1]; v[6] = (short)hi[2]; v[7] = (short)hi[3];
    *(short8*)(yb + b * 1024 + r * 8) = v;
  }
}

// ---------------------------------------------------------------------------
// K3: iDFT + transposed store. grid 4096 = (b 32, n 128), 256 thr.
// Yp layout [n][oq][b][cat][o16]; Yl cat-stride 66 u16 (bank fix).
// ---------------------------------------------------------------------------
__global__ __launch_bounds__(256, 4)
void k3_idft(const unsigned short* __restrict__ Yp, float* __restrict__ out) {
  extern __shared__ char smem[];
  unsigned short* Yl = (unsigned short*)smem;        // [cat 64][66]: o 0..63 + 2 pad
  float* ol = (float*)(smem + 8448);
  const int t = threadIdx.x, lane = t & 63, w = t >> 6;
  const int n = blockIdx.x & 127, b = blockIdx.x >> 7;

  // stage Y: gather 4 oq chunks (each contiguous 2KB) -> Yl[cat*66 + oq*16 + og*8]
  const unsigned short* ysrc = Yp + (n * 4 * 32 + b) * 1024;   // + oq*32768
#pragma unroll
  for (int j = 0; j < 2; ++j) {
    int f = j * 256 + t;
    int og = f & 1, cat = (f >> 1) & 63, oq = f >> 7;
    short8 v = *(const short8*)(ysrc + oq * 32768 + cat * 16 + og * 8);
    unsigned int* d = (unsigned int*)(Yl + cat * 66 + oq * 16 + og * 8);
    union { short8 s; unsigned int u[4]; } uu; uu.s = v;
    d[0] = uu.u[0]; d[1] = uu.u[1]; d[2] = uu.u[2]; d[3] = uu.u[3];
  }

  short8 Af[3][2];
#pragma unroll
  for (int jm = 0; jm < 3; ++jm) {
    int Mt = w + 4 * jm;
    int lt = Mt * 16 + (lane & 15);
#pragma unroll
    for (int kc = 0; kc < 2; ++kc) {
#pragma unroll
      for (int e = 0; e < 8; ++e) {
        int cat = kc * 32 + (lane >> 4) * 8 + e;
        int m = cat >> 1;
        int r = (m * lt) % 192;
        float ang = (float)r * TWO_PI_OVER_L;
        float coef = (m == 0) ? (1.0f / 192.0f) : (2.0f / 192.0f);
        float v = ((cat & 1) ? -__sinf(ang) : __cosf(ang)) * coef;
        Af[jm][kc][e] = (short)f2bf(v);
      }
    }
  }
  __syncthreads();

  f32x4 acc[3][4];
#pragma unroll
  for (int a = 0; a < 3; ++a)
#pragma unroll
    for (int bq = 0; bq < 4; ++bq) acc[a][bq] = zero4();

#pragma unroll
  for (int kc = 0; kc < 2; ++kc) {
    short8 Bf[4];
#pragma unroll
    for (int nt = 0; nt < 4; ++nt)
#pragma unroll
      for (int e = 0; e < 8; ++e) {
        int cat = kc * 32 + (lane >> 4) * 8 + e;
        Bf[nt][e] = (short)Yl[cat * 66 + nt * 16 + (lane & 15)];
      }
#pragma unroll
    for (int jm = 0; jm < 3; ++jm)
#pragma unroll
      for (int nt = 0; nt < 4; ++nt)
        acc[jm][nt] = __builtin_amdgcn_mfma_f32_16x16x32_bf16(Af[jm][kc], Bf[nt], acc[jm][nt], 0, 0, 0);
  }

#pragma unroll
  for (int jm = 0; jm < 3; ++jm) {
    int Mt = w + 4 * jm;
    int l0 = Mt * 16 + (lane >> 4) * 4;
#pragma unroll
    for (int nt = 0; nt < 4; ++nt) {
      int o = nt * 16 + (lane & 15);
      int lp = l0 ^ ((o & 7) << 2);
      *(f32x4*)(ol + o * 192 + lp) = acc[jm][nt];
    }
  }
  __syncthreads();

  float* dst = out + (b * 64 * 128 + n) * 192;
#pragma unroll
  for (int j = 0; j < 12; ++j) {
    int f = j * 256 + t;
    int o = f / 48, g2 = f - o * 48;
    int lp = g2 * 4;
    int l = lp ^ ((o & 7) << 2);
    f32x4 v = *(const f32x4*)(ol + o * 192 + lp);
    *(f32x4*)(dst + o * (128 * 192) + l) = v;
  }
}

// ---------------------------------------------------------------------------
extern "C" void kernel_launch(void* const* d_in, const int* in_sizes, int n_in,
                              void* d_out, int out_size, void* d_ws, size_t ws_size,
                              hipStream_t stream) {
  const float* q  = (const float*)d_in[0];
  const float* wr = (const float*)d_in[1];
  const float* wi = (const float*)d_in[2];
  float* out = (float*)d_out;

  unsigned short* Xp = (unsigned short*)d_ws;            // 33.5 MB
  unsigned short* Yp = Xp + 16777216;                    // 33.5 MB

  hipFuncSetAttribute((const void*)k1_dft,  hipFuncAttributeMaxDynamicSharedMemorySize, 148480);
  hipFuncSetAttribute((const void*)k2g_mix, hipFuncAttributeMaxDynamicSharedMemorySize, 69696);
  hipFuncSetAttribute((const void*)k3_idft, hipFuncAttributeMaxDynamicSharedMemorySize, 57600);

  k1_dft<<<dim3(256), dim3(512), 148480, stream>>>(q, Xp);
  k2g_mix<<<dim3(512), dim3(512), 69696, stream>>>(wr, wi, Xp, Yp);
  k3_idft<<<dim3(4096), dim3(256), 57600, stream>>>(Yp, out);
}

// Round 7
// 193.095 us; speedup vs baseline: 1.2259x; 1.1659x over previous
//
#include <hip/hip_runtime.h>
#include <stdint.h>

// FourierBlock: B=32, D=64, N=128, L=192, M=32 modes.
// Round 7: k1 rebuilt (k1n) around the q-read pathology: q[B,D,N,L] has N
// before L, so per-n staging reads 128B at 98KB stride (row-activate bound,
// ~1.8 TB/s -> ~110us for 201MB). k1n stages FULL 768B l-rows per (b,i) for
// one n at a time (4-n loop per block), fp32 in LDS (no convert on latency
// path), two-loop register pipeline (12 batched loads -> 12 LDS writes).
// k2f/k3 are r4-VERBATIM so total-192 isolates delta(k1).
// ws: Xp 33.5MB @0, Yp 33.5MB @16777216 u16.

typedef __attribute__((ext_vector_type(8))) short short8;
typedef __attribute__((ext_vector_type(4))) float f32x4;
typedef __attribute__((ext_vector_type(4))) unsigned short u16x4;

__device__ __forceinline__ unsigned short f2bf(float f) {
  union { float fv; uint32_t u; } v; v.fv = f;
  uint32_t u = v.u;
  u += 0x7fffu + ((u >> 16) & 1u);          // round-to-nearest-even
  return (unsigned short)(u >> 16);
}

__device__ __forceinline__ f32x4 zero4() { f32x4 z; z[0]=0.f; z[1]=0.f; z[2]=0.f; z[3]=0.f; return z; }

#define TWO_PI_OVER_L (6.283185307179586f / 192.0f)

// ---------------------------------------------------------------------------
// K1n: DFT, q-stride-fixed. grid 512 = (nq 32, bq 8, ih 2), 512 thr (8 waves).
// LDS: qS fp32 [128 rows][196 dw pad] = 100352 B   (row = b_loc*32 + i_loc)
//      Fb bf16 [64 cat][200 u16]      = 25600 B  @ 100352
//      XE bf16 [cat64][b4][i32]       = 16384 B  @ 125952   (total 142336)
// Per n-phase: two-loop stage (12 float4/thread) -> MFMA (A cvt at read) ->
// XE repack -> Xp stores (identical frag layout to all previous rounds).
// ---------------------------------------------------------------------------
__global__ __launch_bounds__(512, 1)
void k1n_dft(const float* __restrict__ q, unsigned short* __restrict__ Xp) {
  extern __shared__ char smem[];
  float* qS = (float*)smem;
  unsigned short* Fb = (unsigned short*)(smem + 100352);
  unsigned short* XE = (unsigned short*)(smem + 125952);
  const int t = threadIdx.x, lane = t & 63, w = t >> 6;
  const int l15 = lane & 15, g = lane >> 4;
  const int bid = blockIdx.x;
  const int ih = bid & 1, bq = (bid >> 1) & 7, nq = bid >> 4;
  const int b0 = bq * 4;

  // DFT basis F[cat][l]: cat=2m+c ; c=0: cos, c=1: -sin (exact int-mod angle)
  for (int idx = t; idx < 64 * 192; idx += 512) {
    int cat = idx / 192, l = idx - cat * 192;
    int m = cat >> 1;
    int r = (m * l) % 192;
    float ang = (float)r * TWO_PI_OVER_L;
    float v = (cat & 1) ? -__sinf(ang) : __cosf(ang);
    Fb[cat * 200 + l] = f2bf(v);
  }

  for (int nn = 0; nn < 4; ++nn) {
    const int n = nq * 4 + nn;

    // ---- loop1: 12 independent float4 loads (batched by compiler)
    float4 stg[12];
#pragma unroll
    for (int j = 0; j < 12; ++j) {
      int fq = (w * 12 + j) * 64 + lane;        // quad id 0..6143
      int row = fq / 48;                         // 0..127
      int qd = fq - row * 48;                    // quad within row
      int b = b0 + (row >> 5);
      int i = ih * 32 + (row & 31);
      stg[j] = *(const float4*)(q + ((size_t)((b * 64 + i) * 128 + n)) * 192 + qd * 4);
    }
    // ---- loop2: write to padded qS (row stride 196 dw)
#pragma unroll
    for (int j = 0; j < 12; ++j) {
      int fq = (w * 12 + j) * 64 + lane;
      int row = fq / 48;
      int qd = fq - row * 48;
      *(float4*)(qS + row * 196 + qd * 4) = stg[j];
    }
    __syncthreads();

    // ---- DFT GEMM: wave w -> Mt = w (rows w*16..w*16+15), cols 64 cat
    f32x4 acc[4];
#pragma unroll
    for (int a = 0; a < 4; ++a) acc[a] = zero4();

    const int row = w * 16 + l15;
#pragma unroll
    for (int kc = 0; kc < 6; ++kc) {
      f32x4 lo = *(const f32x4*)(qS + row * 196 + kc * 32 + g * 8);
      f32x4 hi = *(const f32x4*)(qS + row * 196 + kc * 32 + g * 8 + 4);
      short8 A;
      A[0] = (short)f2bf(lo[0]); A[1] = (short)f2bf(lo[1]);
      A[2] = (short)f2bf(lo[2]); A[3] = (short)f2bf(lo[3]);
      A[4] = (short)f2bf(hi[0]); A[5] = (short)f2bf(hi[1]);
      A[6] = (short)f2bf(hi[2]); A[7] = (short)f2bf(hi[3]);
#pragma unroll
      for (int nt = 0; nt < 4; ++nt) {
        short8 Bf = *(const short8*)(Fb + (nt * 16 + l15) * 200 + kc * 32 + g * 8);
        acc[nt] = __builtin_amdgcn_mfma_f32_16x16x32_bf16(A, Bf, acc[nt], 0, 0, 0);
      }
    }

    // ---- C-frags -> XE[cat][b_loc][i_loc]  (cat*128 + b_loc*32 + i_loc)
    const int b_loc = w >> 1, i_base = (w & 1) * 16 + g * 4;
#pragma unroll
    for (int nt = 0; nt < 4; ++nt) {
      int cat = nt * 16 + l15;
      f32x4 v = acc[nt];
#pragma unroll
      for (int r = 0; r < 4; ++r)
        XE[cat * 128 + b_loc * 32 + i_base + r] = f2bf(v[r]);
    }
    __syncthreads();

    // ---- XE -> Xp global, frag-packed: Xp[n][m][c][ih][Mt2][lane][e8]
    // block writes lanes l15' = (b0&15)+delta, g' 0..3, Mt2 = b0>>4.
#pragma unroll
    for (int cc2 = 0; cc2 < 2; ++cc2) {
      int ch = cc2 * 512 + t;                    // 1024 chunks of 16B
      int m = ch >> 5, c = (ch >> 4) & 1, g2 = (ch >> 2) & 3, dl = ch & 3;
      short8 v = *(const short8*)(XE + (2 * m + c) * 128 + dl * 32 + g2 * 8);
      int lanep = g2 * 16 + (b0 & 15) + dl;
      int off = n * 131072 + ((((m * 2 + c) * 2 + ih) * 2 + (b0 >> 4)) * 64 + lanep) * 8;
      *(short8*)(Xp + off) = v;
    }
    __syncthreads();   // XE/qS safe to overwrite next phase
  }
}

// ---------------------------------------------------------------------------
// K2f: fused W-stage + complex mix. grid 512 = (n 128, oq 4), 512 thr.
// (r4 VERBATIM)
// ---------------------------------------------------------------------------
#define K2_OSTRIDE 34
#define K2_ISTRIDE 546        // 16*34 + 2
#define K2_CSTRIDE 34944      // 64*546
__global__ __launch_bounds__(512, 2)
void k2f_mix(const float* __restrict__ wr, const float* __restrict__ wi,
             const unsigned short* __restrict__ Xp, unsigned short* __restrict__ Yp) {
  extern __shared__ char smem[];
  unsigned short* T = (unsigned short*)smem;
  const int t = threadIdx.x, lane = t & 63, w = t >> 6;
  const int n = blockIdx.x >> 2, oq = blockIdx.x & 3;
  const int ol = lane & 15, il0 = (lane >> 4) * 8;

#pragma unroll
  for (int j = 0; j < 32; ++j) {
    int f = j * 512 + t;
    int mg = f & 7, o = (f >> 3) & 15, i = (f >> 7) & 63, c = (f >> 13) & 1;
    const float* src = (c ? wi : wr) + ((n * 64 + i) * 64 + oq * 16 + o) * 32 + mg * 4;
    float4 v = *(const float4*)src;
    u16x4 h; h[0] = f2bf(v.x); h[1] = f2bf(v.y); h[2] = f2bf(v.z); h[3] = f2bf(v.w);
    *(u16x4*)(T + c * K2_CSTRIDE + i * K2_ISTRIDE + o * K2_OSTRIDE + mg * 4) = h;
  }
  __syncthreads();

#pragma unroll
  for (int mm = 0; mm < 4; ++mm) {
    int m = w * 4 + mm;
    f32x4 acc[2][2];  // [cc][Mt]
#pragma unroll
    for (int a = 0; a < 2; ++a)
#pragma unroll
      for (int b2 = 0; b2 < 2; ++b2) acc[a][b2] = zero4();

#pragma unroll
    for (int ic = 0; ic < 2; ++ic) {
      const unsigned short* xb = Xp + n * 131072 + m * 4096 + ic * 1024 + lane * 8;
      short8 Ar0 = *(const short8*)(xb);
      short8 Ar1 = *(const short8*)(xb + 512);
      short8 Ai0 = *(const short8*)(xb + 2048);
      short8 Ai1 = *(const short8*)(xb + 2048 + 512);

      const unsigned short* tb = T + (ic * 32 + il0) * K2_ISTRIDE + ol * K2_OSTRIDE + m;
      short8 Br, Bi, nBi;
#pragma unroll
      for (int e = 0; e < 8; ++e) {
        Br[e] = (short)tb[e * K2_ISTRIDE];
        Bi[e] = (short)tb[K2_CSTRIDE + e * K2_ISTRIDE];
        nBi[e] = Bi[e] ^ (short)0x8000;   // -Wi
      }

      acc[0][0] = __builtin_amdgcn_mfma_f32_16x16x32_bf16(Ar0, Br,  acc[0][0], 0, 0, 0);
      acc[0][0] = __builtin_amdgcn_mfma_f32_16x16x32_bf16(Ai0, nBi, acc[0][0], 0, 0, 0);
      acc[0][1] = __builtin_amdgcn_mfma_f32_16x16x32_bf16(Ar1, Br,  acc[0][1], 0, 0, 0);
      acc[0][1] = __builtin_amdgcn_mfma_f32_16x16x32_bf16(Ai1, nBi, acc[0][1], 0, 0, 0);
      acc[1][0] = __builtin_amdgcn_mfma_f32_16x16x32_bf16(Ar0, Bi,  acc[1][0], 0, 0, 0);
      acc[1][0] = __builtin_amdgcn_mfma_f32_16x16x32_bf16(Ai0, Br,  acc[1][0], 0, 0, 0);
      acc[1][1] = __builtin_amdgcn_mfma_f32_16x16x32_bf16(Ar1, Bi,  acc[1][1], 0, 0, 0);
      acc[1][1] = __builtin_amdgcn_mfma_f32_16x16x32_bf16(Ai1, Br,  acc[1][1], 0, 0, 0);
    }

    const int g = lane >> 4;
#pragma unroll
    for (int cc = 0; cc < 2; ++cc) {
      int cat = 2 * m + cc;
#pragma unroll
      for (int Mt = 0; Mt < 2; ++Mt) {
        f32x4 v = acc[cc][Mt];
#pragma unroll
        for (int r = 0; r < 4; ++r) {
          int b = Mt * 16 + g * 4 + r;
          Yp[((n * 32 + b) * 64 + cat) * 64 + oq * 16 + ol] = f2bf(v[r]);
        }
      }
    }
  }
}

// ---------------------------------------------------------------------------
// K3: iDFT + transposed store. grid 4096 = (b 32, n 128), 256 thr. (r4 VERBATIM)
// ---------------------------------------------------------------------------
__global__ __launch_bounds__(256, 4)
void k3_idft(const unsigned short* __restrict__ Yp, float* __restrict__ out) {
  extern __shared__ char smem[];
  unsigned short* Yl = (unsigned short*)smem;
  float* ol = (float*)(smem + 8192);
  const int t = threadIdx.x, lane = t & 63, w = t >> 6;
  const int n = blockIdx.x & 127, b = blockIdx.x >> 7;

  const unsigned short* ysrc = Yp + (n * 32 + b) * 4096;
#pragma unroll
  for (int j = 0; j < 2; ++j) {
    int f = j * 256 + t;
    *(short8*)(Yl + f * 8) = *(const short8*)(ysrc + f * 8);
  }

  short8 Af[3][2];
#pragma unroll
  for (int jm = 0; jm < 3; ++jm) {
    int Mt = w + 4 * jm;
    int lt = Mt * 16 + (lane & 15);
#pragma unroll
    for (int kc = 0; kc < 2; ++kc) {
#pragma unroll
      for (int e = 0; e < 8; ++e) {
        int cat = kc * 32 + (lane >> 4) * 8 + e;
        int m = cat >> 1;
        int r = (m * lt) % 192;
        float ang = (float)r * TWO_PI_OVER_L;
        float coef = (m == 0) ? (1.0f / 192.0f) : (2.0f / 192.0f);
        float v = ((cat & 1) ? -__sinf(ang) : __cosf(ang)) * coef;
        Af[jm][kc][e] = (short)f2bf(v);
      }
    }
  }
  __syncthreads();

  f32x4 acc[3][4];
#pragma unroll
  for (int a = 0; a < 3; ++a)
#pragma unroll
    for (int bq = 0; bq < 4; ++bq) acc[a][bq] = zero4();

#pragma unroll
  for (int kc = 0; kc < 2; ++kc) {
    short8 Bf[4];
#pragma unroll
    for (int nt = 0; nt < 4; ++nt)
#pragma unroll
      for (int e = 0; e < 8; ++e) {
        int cat = kc * 32 + (lane >> 4) * 8 + e;
        Bf[nt][e] = (short)Yl[cat * 64 + nt * 16 + (lane & 15)];
      }
#pragma unroll
    for (int jm = 0; jm < 3; ++jm)
#pragma unroll
      for (int nt = 0; nt < 4; ++nt)
        acc[jm][nt] = __builtin_amdgcn_mfma_f32_16x16x32_bf16(Af[jm][kc], Bf[nt], acc[jm][nt], 0, 0, 0);
  }

#pragma unroll
  for (int jm = 0; jm < 3; ++jm) {
    int Mt = w + 4 * jm;
    int l0 = Mt * 16 + (lane >> 4) * 4;
#pragma unroll
    for (int nt = 0; nt < 4; ++nt) {
      int o = nt * 16 + (lane & 15);
      int lp = l0 ^ ((o & 7) << 2);
      *(f32x4*)(ol + o * 192 + lp) = acc[jm][nt];
    }
  }
  __syncthreads();

  float* dst = out + (b * 64 * 128 + n) * 192;
#pragma unroll
  for (int j = 0; j < 12; ++j) {
    int f = j * 256 + t;
    int o = f / 48, g2 = f - o * 48;
    int lp = g2 * 4;
    int l = lp ^ ((o & 7) << 2);
    f32x4 v = *(const f32x4*)(ol + o * 192 + lp);
    *(f32x4*)(dst + o * (128 * 192) + l) = v;
  }
}

// ---------------------------------------------------------------------------
extern "C" void kernel_launch(void* const* d_in, const int* in_sizes, int n_in,
                              void* d_out, int out_size, void* d_ws, size_t ws_size,
                              hipStream_t stream) {
  const float* q  = (const float*)d_in[0];
  const float* wr = (const float*)d_in[1];
  const float* wi = (const float*)d_in[2];
  float* out = (float*)d_out;

  unsigned short* Xp = (unsigned short*)d_ws;            // 33.5 MB
  unsigned short* Yp = Xp + 16777216;                    // 33.5 MB

  hipFuncSetAttribute((const void*)k1n_dft, hipFuncAttributeMaxDynamicSharedMemorySize, 142336);
  hipFuncSetAttribute((const void*)k2f_mix, hipFuncAttributeMaxDynamicSharedMemorySize, 139776);
  hipFuncSetAttribute((const void*)k3_idft, hipFuncAttributeMaxDynamicSharedMemorySize, 57344);

  k1n_dft<<<dim3(512), dim3(512), 142336, stream>>>(q, Xp);
  k2f_mix<<<dim3(512), dim3(512), 139776, stream>>>(wr, wi, Xp, Yp);
  k3_idft<<<dim3(4096), dim3(256), 57344, stream>>>(Yp, out);
}